// Round 3
// baseline (455.393 us; speedup 1.0000x reference)
//
#include <hip/hip_runtime.h>
#include <stdint.h>

#define S_MAX 36500.0f
#define S_MIN 0.01f

#define SEQ     512
#define BATCH   65536
#define TT      16                    // t-steps per tile
#define BLK     256                   // threads per block = columns per block
#define ROWB    (BLK * 8)             // bytes per tile row (256 cols * float2) = 2048
#define TILEB   (TT * ROWB)           // 32 KB per buffer
#define NTILES  (SEQ / TT)            // 32
#define RPW     (TT / 4)              // rows per wave = 4

typedef __attribute__((address_space(3))) uint8_t       lds_byte;
typedef __attribute__((address_space(1))) const uint8_t glob_byte;

// Cooperative global->LDS DMA: wave w loads rows [w*RPW, w*RPW+RPW), each row
// 2048 B = 2 x (64 lanes * 16 B) contiguous global_load_lds_dwordx4.
__device__ __forceinline__ void load_tile_async(const uint8_t* g0, uint8_t* l0,
                                                int wave, int lane, size_t row_stride) {
#pragma unroll
    for (int j = 0; j < RPW; ++j) {
        const int r = wave * RPW + j;
        const uint8_t* g = g0 + (size_t)r * row_stride;
        uint8_t*       l = l0 + (size_t)r * ROWB;
        __builtin_amdgcn_global_load_lds((glob_byte*)(g + lane * 16),
                                         (lds_byte*)(l + lane * 16), 16, 0, 0);
        __builtin_amdgcn_global_load_lds((glob_byte*)(g + 1024 + lane * 16),
                                         (lds_byte*)(l + 1024 + lane * 16), 16, 0, 0);
    }
}

// Cooperative LDS->global store, same row ownership, dwordx4 per lane.
__device__ __forceinline__ void store_tile(uint8_t* g0, const uint8_t* l0,
                                           int wave, int lane, size_t row_stride) {
#pragma unroll
    for (int j = 0; j < RPW; ++j) {
        const int r = wave * RPW + j;
        uint8_t*       g = g0 + (size_t)r * row_stride;
        const uint8_t* l = l0 + (size_t)r * ROWB;
        const float4 v0 = *(const float4*)(l + lane * 16);
        const float4 v1 = *(const float4*)(l + 1024 + lane * 16);
        *(float4*)(g + lane * 16)        = v0;
        *(float4*)(g + 1024 + lane * 16) = v1;
    }
}

__global__ __launch_bounds__(BLK) void anki_scan(
    const float* __restrict__ inputs,  // [SEQ][BATCH][2]
    const float* __restrict__ w,       // [7]
    float* __restrict__ out)           // [SEQ][BATCH][2] then [BATCH][2]
{
#pragma clang fp contract(off)
    __shared__ uint8_t lds[2][TILEB];

    const int tid  = threadIdx.x;
    const int wave = tid >> 6;
    const int lane = tid & 63;
    const int blk  = blockIdx.x;

    const size_t row_stride = (size_t)BATCH * 8;   // bytes per t-row
    const uint8_t* gin = (const uint8_t*)inputs + (size_t)blk * BLK * 8;
    uint8_t*      gout = (uint8_t*)out          + (size_t)blk * BLK * 8;

    const float w0 = w[0], w1 = w[1], w2 = w[2], w3 = w[3];
    const float w4 = w[4], w5 = w[5], w6 = w[6];

    float ivl = 0.0f, ease = 0.0f;

    // Prologue: tiles 0 and 1 in flight.
    load_tile_async(gin,                               (uint8_t*)lds[0], wave, lane, row_stride);
    load_tile_async(gin + (size_t)TT * row_stride,     (uint8_t*)lds[1], wave, lane, row_stride);

    for (int k = 0; k < NTILES; ++k) {
        uint8_t* cur = (uint8_t*)lds[k & 1];
        __syncthreads();                 // vmcnt drain: cur tile resident

        float2* tile = (float2*)cur;

        float2 xs[TT];
#pragma unroll
        for (int r = 0; r < TT; ++r) xs[r] = tile[r * BLK + tid];

#pragma unroll
        for (int r = 0; r < TT; ++r) {
            const float delta_t = xs[r].x;
            const float rating  = xs[r].y;

            const bool is_first = (ivl == 0.0f) || (ease == 0.0f);

            float ne = ease;
            ne = (rating == 1.0f) ? ease - 0.2f  : ne;
            ne = (rating == 2.0f) ? ease - 0.15f : ne;
            ne = (rating == 4.0f) ? ease + 0.15f : ne;
            ne = fminf(fmaxf(ne, 1.3f), 5.5f);

            const float days_late = delta_t - ivl;
            const bool pass_cond  = rating > 1.0f;
            const bool early      = pass_cond && (days_late <  0.0f);
            const bool non_early  = pass_cond && (days_late >= 0.0f);

            const float elapsed = ivl + days_late;
            const float e_hard  = fmaxf(elapsed * w4, ivl * w4 * 0.5f);
            const float e_good  = ivl * ne;
            const float e_easy  = e_good * w3;
            const float ivl_early =
                (rating == 2.0f) ? e_hard : ((rating == 4.0f) ? e_easy : e_good);

            const float n_hard = ivl * w4;
            const float n_good = (ivl + days_late * 0.5f)  * ne;
            const float n_easy = (ivl + days_late * 0.25f) * ne * w3;
            const float ivl_non_early =
                (rating == 2.0f) ? n_hard : ((rating == 4.0f) ? n_easy : n_good);

            const float calc =
                (early ? ivl_early : (non_early ? ivl_non_early : 0.0f)) * w6;

            float new_ivl = pass_cond ? calc : ivl;
            new_ivl = (rating == 1.0f) ? ivl * w5 : new_ivl;
            new_ivl = (is_first && rating <  4.0f) ? w0 : new_ivl;
            new_ivl = (is_first && rating == 4.0f) ? w1 : new_ivl;
            ne      = is_first ? w2 : ne;
            new_ivl = fminf(fmaxf(new_ivl, S_MIN), S_MAX);

            tile[r * BLK + tid] = make_float2(new_ivl, ne);
            ivl  = new_ivl;
            ease = ne;
        }

        __syncthreads();                 // all results of this tile in LDS

        store_tile(gout + (size_t)k * TT * row_stride, cur, wave, lane, row_stride);

        // Refill the buffer just consumed (wave-local rows: the ds_reads feeding
        // the stores above are program-ordered before these LDS writes).
        if (k + 2 < NTILES)
            load_tile_async(gin + (size_t)(k + 2) * TT * row_stride, cur, wave, lane, row_stride);
    }

    // Final state: [BATCH][2] appended after the per-step outputs.
    float2* fin2 = (float2*)((uint8_t*)out + (size_t)SEQ * row_stride);
    fin2[blk * BLK + tid] = make_float2(ivl, ease);
}

extern "C" void kernel_launch(void* const* d_in, const int* in_sizes, int n_in,
                              void* d_out, int out_size, void* d_ws, size_t ws_size,
                              hipStream_t stream) {
    const float* inputs = (const float*)d_in[0];
    const float* w      = (const float*)d_in[1];
    float* out          = (float*)d_out;

    anki_scan<<<BATCH / BLK, BLK, 0, stream>>>(inputs, w, out);
}